// Round 1
// baseline (211.637 us; speedup 1.0000x reference)
//
#include <hip/hip_runtime.h>
#include <math.h>

#define NPTS 50000
#define NQ   4000
#define KNN  4

// One 64-lane wave per query. Each lane scans points with stride 64 keeping a
// sorted top-4 (dist, idx); a 6-step shfl_xor butterfly merges lanes with
// lexicographic (dist, idx) compare to match jax.lax.top_k tie-breaking
// (lower index first on equal values).
__global__ __launch_bounds__(256) void knn_kernel(const float* __restrict__ points,
                                                  const float* __restrict__ queries,
                                                  float* __restrict__ out) {
    const int gtid = blockIdx.x * blockDim.x + threadIdx.x;
    const int wave = gtid >> 6;
    const int lane = threadIdx.x & 63;
    if (wave >= NQ) return;

    const float q0 = queries[wave * 3 + 0];
    const float q1 = queries[wave * 3 + 1];
    const float q2 = queries[wave * 3 + 2];
    // q2s = (q0*q0 + q1*q1) + q2*q2  -- exact IEEE ops, no FMA contraction
    const float q2s = __fadd_rn(__fadd_rn(__fmul_rn(q0, q0), __fmul_rn(q1, q1)),
                                __fmul_rn(q2, q2));

    float bd[KNN];
    int   bi[KNN];
#pragma unroll
    for (int j = 0; j < KNN; ++j) { bd[j] = INFINITY; bi[j] = 0x7FFFFFFF; }

    for (int p = lane; p < NPTS; p += 64) {
        const float p0 = points[p * 3 + 0];
        const float p1 = points[p * 3 + 1];
        const float p2 = points[p * 3 + 2];
        const float p2s = __fadd_rn(__fadd_rn(__fmul_rn(p0, p0), __fmul_rn(p1, p1)),
                                    __fmul_rn(p2, p2));
        const float dot = __fadd_rn(__fadd_rn(__fmul_rn(q0, p0), __fmul_rn(q1, p1)),
                                    __fmul_rn(q2, p2));
        float d2 = __fsub_rn(__fadd_rn(q2s, p2s), __fmul_rn(2.0f, dot));
        d2 = fmaxf(d2, 0.0f);
        const float dist = __fsqrt_rn(d2);

        // Insert into sorted top-4 (ascending). Strict < keeps earlier (lower)
        // index first on exact ties, since p increases within the lane.
        if (dist < bd[KNN - 1]) {
            bd[KNN - 1] = dist;
            bi[KNN - 1] = p;
#pragma unroll
            for (int j = KNN - 1; j > 0; --j) {
                if (bd[j] < bd[j - 1]) {
                    float td = bd[j]; bd[j] = bd[j - 1]; bd[j - 1] = td;
                    int   ti = bi[j]; bi[j] = bi[j - 1]; bi[j - 1] = ti;
                }
            }
        }
    }

    // Butterfly merge across the 64 lanes; every lane ends with the global top-4.
    for (int m = 1; m < 64; m <<= 1) {
        float od[KNN];
        int   oi[KNN];
#pragma unroll
        for (int j = 0; j < KNN; ++j) {
            od[j] = __shfl_xor(bd[j], m, 64);
            oi[j] = __shfl_xor(bi[j], m, 64);
        }
        // Merge two sorted 4-lists, keep smallest 4. Lexicographic (dist, idx).
        float md[KNN];
        int   mi[KNN];
        int a = 0, b = 0;
#pragma unroll
        for (int j = 0; j < KNN; ++j) {
            const bool takeA = (bd[a] < od[b]) || (bd[a] == od[b] && bi[a] <= oi[b]);
            if (takeA) { md[j] = bd[a]; mi[j] = bi[a]; ++a; }
            else       { md[j] = od[b]; mi[j] = oi[b]; ++b; }
        }
#pragma unroll
        for (int j = 0; j < KNN; ++j) { bd[j] = md[j]; bi[j] = mi[j]; }
    }

    if (lane == 0) {
#pragma unroll
        for (int j = 0; j < KNN; ++j) {
            out[wave * KNN + j]             = bd[j];           // distances
            out[NQ * KNN + wave * KNN + j]  = (float)bi[j];    // indices as f32
        }
    }
}

extern "C" void kernel_launch(void* const* d_in, const int* in_sizes, int n_in,
                              void* d_out, int out_size, void* d_ws, size_t ws_size,
                              hipStream_t stream) {
    const float* points  = (const float*)d_in[0];
    const float* queries = (const float*)d_in[1];
    float* out = (float*)d_out;

    // 4000 waves, 4 waves (256 threads) per block -> 1000 blocks
    const int threads = 256;
    const int waves_per_block = threads / 64;
    const int blocks = (NQ + waves_per_block - 1) / waves_per_block;
    knn_kernel<<<blocks, threads, 0, stream>>>(points, queries, out);
}

// Round 2
// 206.318 us; speedup vs baseline: 1.0258x; 1.0258x over previous
//
#include <hip/hip_runtime.h>
#include <math.h>
#include <limits.h>

#define NPTS   50000
#define NPAD   50176            // 64*784 = 256*196; padded with sentinels
#define NQ     4000
#define KNN    4
#define CHUNK  25088            // NPAD/2, = 64*392 -> 98 groups of 256
#define NGROUP 98
#define CAP    16
#define NWAVE  (NQ * 2)

// workspace layout (bytes)
#define PK_OFF  0
#define CNT_OFF (NPAD * 16)                       // 802816
#define DL_OFF  (CNT_OFF + NWAVE * 4)             // 834816
#define IL_OFF  (DL_OFF + NWAVE * CAP * 4)        // 1346816
#define WS_NEED (IL_OFF + NWAVE * CAP * 4)        // 1858816 (~1.86 MB)

// Exact same arithmetic as the reference expansion (no FMA contraction):
// dot = (q0*x + q1*y) + q2*z ; d2 = (q2s + p2s) - 2*dot
__device__ __forceinline__ float d2_of(float q0, float q1, float q2v, float q2s, float4 P) {
    float dot = __fadd_rn(__fadd_rn(__fmul_rn(q0, P.x), __fmul_rn(q1, P.y)),
                          __fmul_rn(q2v, P.z));
    return __fsub_rn(__fadd_rn(q2s, P.w), __fmul_rn(2.0f, dot));
}

// ---------------- pack: points [N,3] -> float4 {x,y,z,p2s}, sentinel pad ----
__global__ __launch_bounds__(256) void pack_kernel(const float* __restrict__ pts,
                                                   float4* __restrict__ packed) {
    int t = blockIdx.x * 256 + threadIdx.x;
    if (t >= NPAD) return;
    if (t < NPTS) {
        float x = pts[3 * t], y = pts[3 * t + 1], z = pts[3 * t + 2];
        float s = __fadd_rn(__fadd_rn(__fmul_rn(x, x), __fmul_rn(y, y)),
                            __fmul_rn(z, z));
        packed[t] = make_float4(x, y, z, s);
    } else {
        packed[t] = make_float4(0.f, 0.f, 0.f, 3.0e38f);  // d2 ~ 3e38, never selected
    }
}

// ---------------- main: pass A (min-scan -> tau), pass B (filter+push) ------
__global__ __launch_bounds__(256) void knn_main(const float4* __restrict__ pk,
                                                const float* __restrict__ queries,
                                                int* __restrict__ cnt,
                                                float* __restrict__ dl,
                                                int* __restrict__ il) {
    const int w    = blockIdx.x * 4 + (threadIdx.x >> 6);   // wave id, [0, 8000)
    const int lane = threadIdx.x & 63;
    const int q    = w >> 1;
    const int base = (w & 1) * CHUNK;

    const float q0  = queries[q * 3 + 0];
    const float q1  = queries[q * 3 + 1];
    const float q2v = queries[q * 3 + 2];
    const float q2s = __fadd_rn(__fadd_rn(__fmul_rn(q0, q0), __fmul_rn(q1, q1)),
                                __fmul_rn(q2v, q2v));

    // ---- pass A: branchless per-lane min of d2 over my strided points ----
    const float4* p = pk + base + lane;
    float mn = 3.0e38f;
#pragma unroll 2
    for (int g = 0; g < NGROUP; ++g) {
        float4 a = p[0], b = p[64], c = p[128], d = p[192];
        p += 256;
        float da = d2_of(q0, q1, q2v, q2s, a);
        float db = d2_of(q0, q1, q2v, q2s, b);
        float dc = d2_of(q0, q1, q2v, q2s, c);
        float dd = d2_of(q0, q1, q2v, q2s, d);
        mn = fminf(mn, fminf(fminf(da, db), fminf(dc, dd)));
    }

    // tau = 4th-distinct-smallest of the 64 lane mins (upper bound on true 4th-NN d2:
    // at least 4 distinct points have d2 <= tau).
    float v = mn, tau = mn;
#pragma unroll
    for (int r = 0; r < 4; ++r) {
        float t = v;
#pragma unroll
        for (int s = 1; s < 64; s <<= 1) t = fminf(t, __shfl_xor(t, s, 64));
        tau = t;
        v = (v == t) ? 3.0e38f : v;   // mask this round's winner(s)
    }
    // Inclusive boundary in the *dist* domain: capture every point whose
    // sqrt_rn(max(d2,0)) <= sqrt_rn(max(tau,0)). Margin 2e-6 rel >> 1 ulp slack,
    // over-captures (harmless: final pass sorts exactly), never under-captures.
    float tdist = __fsqrt_rn(fmaxf(tau, 0.f));
    float tau2  = __fmul_rn(__fmul_rn(tdist, tdist), 1.000002f);
    if (tau2 < tau) tau2 = tau;   // keep the >=4-candidates guarantee

    // ---- pass B: rescan, rare push of candidates ----
    p = pk + base + lane;
    int pb = base + lane;
#pragma unroll 2
    for (int g = 0; g < NGROUP; ++g) {
        float4 a = p[0], b = p[64], c = p[128], d = p[192];
        p += 256;
        float da = d2_of(q0, q1, q2v, q2s, a);
        float db = d2_of(q0, q1, q2v, q2s, b);
        float dc = d2_of(q0, q1, q2v, q2s, c);
        float dd = d2_of(q0, q1, q2v, q2s, d);
        float m4 = fminf(fminf(da, db), fminf(dc, dd));
        if (m4 <= tau2) {
            if (da <= tau2) { int pos = atomicAdd(&cnt[w], 1); if (pos < CAP) { dl[w*CAP+pos] = da; il[w*CAP+pos] = pb; } }
            if (db <= tau2) { int pos = atomicAdd(&cnt[w], 1); if (pos < CAP) { dl[w*CAP+pos] = db; il[w*CAP+pos] = pb + 64; } }
            if (dc <= tau2) { int pos = atomicAdd(&cnt[w], 1); if (pos < CAP) { dl[w*CAP+pos] = dc; il[w*CAP+pos] = pb + 128; } }
            if (dd <= tau2) { int pos = atomicAdd(&cnt[w], 1); if (pos < CAP) { dl[w*CAP+pos] = dd; il[w*CAP+pos] = pb + 192; } }
        }
        pb += 256;
    }
}

// ---------------- final: exact (dist, idx) top-4 over the candidates --------
__global__ __launch_bounds__(256) void knn_final(const int* __restrict__ cnt,
                                                 const float* __restrict__ dl,
                                                 const int* __restrict__ il,
                                                 float* __restrict__ out) {
    int q = blockIdx.x * 256 + threadIdx.x;
    if (q >= NQ) return;
    float bd[KNN];
    int   bi[KNN];
#pragma unroll
    for (int j = 0; j < KNN; ++j) { bd[j] = INFINITY; bi[j] = INT_MAX; }

    for (int h = 0; h < 2; ++h) {
        int wq = q * 2 + h;
        int c  = cnt[wq]; if (c > CAP) c = CAP;
        for (int j = 0; j < c; ++j) {
            float d2   = dl[wq * CAP + j];
            int   idx  = il[wq * CAP + j];
            float dist = __fsqrt_rn(fmaxf(d2, 0.f));
            bool take = (dist < bd[KNN-1]) || (dist == bd[KNN-1] && idx < bi[KNN-1]);
            if (take) {
                bd[KNN-1] = dist; bi[KNN-1] = idx;
#pragma unroll
                for (int k = KNN - 1; k > 0; --k) {
                    bool sw = (bd[k] < bd[k-1]) || (bd[k] == bd[k-1] && bi[k] < bi[k-1]);
                    if (sw) {
                        float td = bd[k]; bd[k] = bd[k-1]; bd[k-1] = td;
                        int   ti = bi[k]; bi[k] = bi[k-1]; bi[k-1] = ti;
                    }
                }
            }
        }
    }
#pragma unroll
    for (int j = 0; j < KNN; ++j) {
        out[q * KNN + j]            = bd[j];
        out[NQ * KNN + q * KNN + j] = (float)bi[j];
    }
}

// ---------------- fallback (round-1 kernel) if ws is too small --------------
__global__ __launch_bounds__(256) void knn_fallback(const float* __restrict__ points,
                                                    const float* __restrict__ queries,
                                                    float* __restrict__ out) {
    const int gtid = blockIdx.x * blockDim.x + threadIdx.x;
    const int wave = gtid >> 6;
    const int lane = threadIdx.x & 63;
    if (wave >= NQ) return;
    const float q0 = queries[wave*3+0], q1 = queries[wave*3+1], q2v = queries[wave*3+2];
    const float q2s = __fadd_rn(__fadd_rn(__fmul_rn(q0,q0), __fmul_rn(q1,q1)), __fmul_rn(q2v,q2v));
    float bd[KNN]; int bi[KNN];
#pragma unroll
    for (int j = 0; j < KNN; ++j) { bd[j] = INFINITY; bi[j] = INT_MAX; }
    for (int p = lane; p < NPTS; p += 64) {
        float x = points[p*3], y = points[p*3+1], z = points[p*3+2];
        float p2s = __fadd_rn(__fadd_rn(__fmul_rn(x,x), __fmul_rn(y,y)), __fmul_rn(z,z));
        float dot = __fadd_rn(__fadd_rn(__fmul_rn(q0,x), __fmul_rn(q1,y)), __fmul_rn(q2v,z));
        float d2 = __fsub_rn(__fadd_rn(q2s, p2s), __fmul_rn(2.0f, dot));
        float dist = __fsqrt_rn(fmaxf(d2, 0.f));
        if (dist < bd[KNN-1]) {
            bd[KNN-1] = dist; bi[KNN-1] = p;
#pragma unroll
            for (int j = KNN-1; j > 0; --j)
                if (bd[j] < bd[j-1]) { float td=bd[j];bd[j]=bd[j-1];bd[j-1]=td; int ti=bi[j];bi[j]=bi[j-1];bi[j-1]=ti; }
        }
    }
    for (int m = 1; m < 64; m <<= 1) {
        float od[KNN]; int oi[KNN];
#pragma unroll
        for (int j = 0; j < KNN; ++j) { od[j] = __shfl_xor(bd[j], m, 64); oi[j] = __shfl_xor(bi[j], m, 64); }
        float md[KNN]; int mi[KNN]; int a = 0, b = 0;
#pragma unroll
        for (int j = 0; j < KNN; ++j) {
            bool takeA = (bd[a] < od[b]) || (bd[a] == od[b] && bi[a] <= oi[b]);
            if (takeA) { md[j]=bd[a]; mi[j]=bi[a]; ++a; } else { md[j]=od[b]; mi[j]=oi[b]; ++b; }
        }
#pragma unroll
        for (int j = 0; j < KNN; ++j) { bd[j]=md[j]; bi[j]=mi[j]; }
    }
    if (lane == 0) {
#pragma unroll
        for (int j = 0; j < KNN; ++j) {
            out[wave*KNN+j] = bd[j];
            out[NQ*KNN + wave*KNN + j] = (float)bi[j];
        }
    }
}

extern "C" void kernel_launch(void* const* d_in, const int* in_sizes, int n_in,
                              void* d_out, int out_size, void* d_ws, size_t ws_size,
                              hipStream_t stream) {
    const float* points  = (const float*)d_in[0];
    const float* queries = (const float*)d_in[1];
    float* out = (float*)d_out;

    if (ws_size < (size_t)WS_NEED) {
        knn_fallback<<<(NQ * 64 + 255) / 256, 256, 0, stream>>>(points, queries, out);
        return;
    }

    char* ws = (char*)d_ws;
    float4* packed = (float4*)(ws + PK_OFF);
    int*    cnt    = (int*)(ws + CNT_OFF);
    float*  dl     = (float*)(ws + DL_OFF);
    int*    il     = (int*)(ws + IL_OFF);

    pack_kernel<<<NPAD / 256, 256, 0, stream>>>(points, packed);
    hipMemsetAsync(cnt, 0, NWAVE * sizeof(int), stream);
    knn_main<<<NWAVE / 4, 256, 0, stream>>>(packed, queries, cnt, dl, il);
    knn_final<<<(NQ + 255) / 256, 256, 0, stream>>>(cnt, dl, il, out);
}

// Round 6
// 132.807 us; speedup vs baseline: 1.5936x; 1.5535x over previous
//
#include <hip/hip_runtime.h>
#include <math.h>
#include <limits.h>

#define NPTS    50000
#define NPAD    50176            // 4 chunks * 12544; 12544 = 49*256; pad=176 sentinels
#define NQ      4000
#define KNN     4
#define NCHUNK  4
#define CHUNK   12544
#define NGROUP  49
#define QG      4                // queries per wave
#define NWAVE   4000             // (NQ/QG) * NCHUNK
#define CAP     14               // per-(query,chunk) candidate pool
#define BIGF    3.0e38f

// workspace layout (bytes)
#define PK_OFF  0
#define CNT_OFF (NPAD * 16)                         // 802816
#define DL_OFF  (CNT_OFF + NQ * NCHUNK * 4)         // 866816
#define IL_OFF  (DL_OFF + NQ * NCHUNK * CAP * 4)    // 1762816
#define WS_NEED (IL_OFF + NQ * NCHUNK * CAP * 4)    // 2658816 (~2.66 MB; ws >= 2.89 MB proven)

// EXACT round-2 (passing) arithmetic: packed P = {x, y, z, p2s}
// dot = (q0*x + q1*y) + q2*z ; d2 = (q2s + p2s) - 2*dot   (no FMA contraction)
__device__ __forceinline__ float d2_of(float qx, float qy, float qz, float qs, float4 P) {
    float dot = __fadd_rn(__fadd_rn(__fmul_rn(qx, P.x), __fmul_rn(qy, P.y)),
                          __fmul_rn(qz, P.z));
    return __fsub_rn(__fadd_rn(qs, P.w), __fmul_rn(2.0f, dot));
}

// lex (dist, idx) insert into sorted ascending 4-list
__device__ __forceinline__ void lex_insert(float (&bd)[KNN], int (&bi)[KNN],
                                           float dist, int idx) {
    if (dist < bd[KNN - 1] || (dist == bd[KNN - 1] && idx < bi[KNN - 1])) {
        bd[KNN - 1] = dist; bi[KNN - 1] = idx;
#pragma unroll
        for (int k = KNN - 1; k > 0; --k) {
            bool sw = (bd[k] < bd[k - 1]) || (bd[k] == bd[k - 1] && bi[k] < bi[k - 1]);
            if (sw) {
                float td = bd[k]; bd[k] = bd[k - 1]; bd[k - 1] = td;
                int   ti = bi[k]; bi[k] = bi[k - 1]; bi[k - 1] = ti;
            }
        }
    }
}

// ---------------- pack: [N,3] -> {x,y,z,p2s}, sentinel pad (round-2 exact) --
__global__ __launch_bounds__(256) void pack_kernel(const float* __restrict__ pts,
                                                   float4* __restrict__ packed) {
    int t = blockIdx.x * 256 + threadIdx.x;   // grid = NPAD/256 = 196, covers exactly
    if (t < NPTS) {
        float x = pts[3 * t], y = pts[3 * t + 1], z = pts[3 * t + 2];
        float s = __fadd_rn(__fadd_rn(__fmul_rn(x, x), __fmul_rn(y, y)),
                            __fmul_rn(z, z));
        packed[t] = make_float4(x, y, z, s);
    } else {
        packed[t] = make_float4(0.f, 0.f, 0.f, BIGF);   // never passes tau filter
    }
}

// ---------------- main: pass A (min -> tau2 per query), pass B (atomic push)
__global__ __launch_bounds__(256) void knn_main(const float4* __restrict__ pk,
                                                const float* __restrict__ queries,
                                                int* __restrict__ cnt,
                                                float* __restrict__ dl,
                                                int* __restrict__ il) {
    const int w     = blockIdx.x * 4 + (threadIdx.x >> 6);  // [0, 4000)
    const int lane  = threadIdx.x & 63;
    const int qg    = w >> 2;            // query group [0, 1000)
    const int chunk = w & 3;
    const int qbase = qg * QG;

    float qx[QG], qy[QG], qz[QG], qs[QG];
#pragma unroll
    for (int j = 0; j < QG; ++j) {
        float a = queries[(qbase + j) * 3 + 0];
        float b = queries[(qbase + j) * 3 + 1];
        float c = queries[(qbase + j) * 3 + 2];
        qx[j] = a; qy[j] = b; qz[j] = c;
        qs[j] = __fadd_rn(__fadd_rn(__fmul_rn(a, a), __fmul_rn(b, b)),
                          __fmul_rn(c, c));
    }

    // ---- pass A: per-lane min of d2 per query (round-2 loop structure) ----
    const float4* p = pk + chunk * CHUNK + lane;
    float mn[QG];
#pragma unroll
    for (int j = 0; j < QG; ++j) mn[j] = BIGF;

#pragma unroll 1
    for (int g = 0; g < NGROUP; ++g) {
        float4 a = p[0], b = p[64], c = p[128], d = p[192];   // read, then advance
        p += 256;
#pragma unroll
        for (int j = 0; j < QG; ++j) {
            float da = d2_of(qx[j], qy[j], qz[j], qs[j], a);
            float db = d2_of(qx[j], qy[j], qz[j], qs[j], b);
            float dc = d2_of(qx[j], qy[j], qz[j], qs[j], c);
            float dd = d2_of(qx[j], qy[j], qz[j], qs[j], d);
            mn[j] = fminf(mn[j], fminf(fminf(da, db), fminf(dc, dd)));
        }
    }

    // ---- tau2 per query: 4th-distinct-smallest of 64 lane mins + slack ----
    float tau2[QG];
#pragma unroll
    for (int j = 0; j < QG; ++j) {
        float v = mn[j], tau = mn[j];
#pragma unroll
        for (int r = 0; r < 4; ++r) {
            float t = v;
#pragma unroll
            for (int s = 1; s < 64; s <<= 1) t = fminf(t, __shfl_xor(t, s, 64));
            tau = t;
            v = (v == t) ? BIGF : v;
        }
        float tdist = __fsqrt_rn(fmaxf(tau, 0.f));
        float t2 = __fmul_rn(__fmul_rn(tdist, tdist), 1.000002f);
        tau2[j] = (t2 < tau) ? tau : t2;
    }

    // ---- pass B: rescan, rare atomic pushes into per-(query,chunk) pool ----
    p = pk + chunk * CHUNK + lane;
    int pb = chunk * CHUNK + lane;
#pragma unroll 1
    for (int g = 0; g < NGROUP; ++g) {
        float4 a = p[0], b = p[64], c = p[128], d = p[192];
        p += 256;
#pragma unroll
        for (int j = 0; j < QG; ++j) {
            float da = d2_of(qx[j], qy[j], qz[j], qs[j], a);
            float db = d2_of(qx[j], qy[j], qz[j], qs[j], b);
            float dc = d2_of(qx[j], qy[j], qz[j], qs[j], c);
            float dd = d2_of(qx[j], qy[j], qz[j], qs[j], d);
            float t4 = fminf(fminf(da, db), fminf(dc, dd));
            if (t4 <= tau2[j]) {
                const int pool = (qbase + j) * NCHUNK + chunk;
                if (da <= tau2[j]) { int pos = atomicAdd(&cnt[pool], 1); if (pos >= 0 && pos < CAP) { dl[pool*CAP+pos] = da; il[pool*CAP+pos] = pb; } }
                if (db <= tau2[j]) { int pos = atomicAdd(&cnt[pool], 1); if (pos >= 0 && pos < CAP) { dl[pool*CAP+pos] = db; il[pool*CAP+pos] = pb + 64; } }
                if (dc <= tau2[j]) { int pos = atomicAdd(&cnt[pool], 1); if (pos >= 0 && pos < CAP) { dl[pool*CAP+pos] = dc; il[pool*CAP+pos] = pb + 128; } }
                if (dd <= tau2[j]) { int pos = atomicAdd(&cnt[pool], 1); if (pos >= 0 && pos < CAP) { dl[pool*CAP+pos] = dd; il[pool*CAP+pos] = pb + 192; } }
            }
        }
        pb += 256;
    }
}

// ---------------- final: per-THREAD merge of 4 pools (round-2 style) --------
__global__ __launch_bounds__(256) void knn_final(const int* __restrict__ cnt,
                                                 const float* __restrict__ dl,
                                                 const int* __restrict__ il,
                                                 const float* __restrict__ points,
                                                 const float* __restrict__ queries,
                                                 float* __restrict__ out) {
    const int q = blockIdx.x * 256 + threadIdx.x;
    if (q >= NQ) return;

    float bd[KNN]; int bi[KNN];
#pragma unroll
    for (int k = 0; k < KNN; ++k) { bd[k] = INFINITY; bi[k] = INT_MAX; }

    bool ovf = false;
#pragma unroll
    for (int c = 0; c < NCHUNK; ++c) ovf = ovf || (cnt[q * NCHUNK + c] > CAP);

    if (!ovf) {
#pragma unroll 1
        for (int c = 0; c < NCHUNK; ++c) {
            const int pool = q * NCHUNK + c;
            const int n = cnt[pool];
            for (int j = 0; j < n; ++j) {
                float dist = __fsqrt_rn(fmaxf(dl[pool * CAP + j], 0.f));
                lex_insert(bd, bi, dist, il[pool * CAP + j]);
            }
        }
    } else {
        // overflow repair (expected never): scalar brute-force, exact arithmetic
        const float q0 = queries[q*3+0], q1 = queries[q*3+1], q2v = queries[q*3+2];
        const float q2s = __fadd_rn(__fadd_rn(__fmul_rn(q0,q0), __fmul_rn(q1,q1)),
                                    __fmul_rn(q2v,q2v));
        for (int p = 0; p < NPTS; ++p) {
            float x = points[p*3], y = points[p*3+1], z = points[p*3+2];
            float p2s = __fadd_rn(__fadd_rn(__fmul_rn(x,x), __fmul_rn(y,y)), __fmul_rn(z,z));
            float dot = __fadd_rn(__fadd_rn(__fmul_rn(q0,x), __fmul_rn(q1,y)), __fmul_rn(q2v,z));
            float d2 = __fsub_rn(__fadd_rn(q2s, p2s), __fmul_rn(2.0f, dot));
            lex_insert(bd, bi, __fsqrt_rn(fmaxf(d2, 0.f)), p);
        }
    }

#pragma unroll
    for (int k = 0; k < KNN; ++k) {
        out[q * KNN + k]            = bd[k];
        out[NQ * KNN + q * KNN + k] = (float)bi[k];
    }
}

// ---------------- fallback (round-1 kernel, passed) if ws too small ---------
__global__ __launch_bounds__(256) void knn_fallback(const float* __restrict__ points,
                                                    const float* __restrict__ queries,
                                                    float* __restrict__ out) {
    const int gtid = blockIdx.x * blockDim.x + threadIdx.x;
    const int wave = gtid >> 6;
    const int lane = threadIdx.x & 63;
    if (wave >= NQ) return;
    const float q0 = queries[wave*3+0], q1 = queries[wave*3+1], q2v = queries[wave*3+2];
    const float q2s = __fadd_rn(__fadd_rn(__fmul_rn(q0,q0), __fmul_rn(q1,q1)), __fmul_rn(q2v,q2v));
    float bd[KNN]; int bi[KNN];
#pragma unroll
    for (int j = 0; j < KNN; ++j) { bd[j] = INFINITY; bi[j] = INT_MAX; }
    for (int p = lane; p < NPTS; p += 64) {
        float x = points[p*3], y = points[p*3+1], z = points[p*3+2];
        float p2s = __fadd_rn(__fadd_rn(__fmul_rn(x,x), __fmul_rn(y,y)), __fmul_rn(z,z));
        float dot = __fadd_rn(__fadd_rn(__fmul_rn(q0,x), __fmul_rn(q1,y)), __fmul_rn(q2v,z));
        float d2 = __fsub_rn(__fadd_rn(q2s, p2s), __fmul_rn(2.0f, dot));
        lex_insert(bd, bi, __fsqrt_rn(fmaxf(d2, 0.f)), p);
    }
    for (int m = 1; m < 64; m <<= 1) {
        float od[KNN]; int oi[KNN];
#pragma unroll
        for (int j = 0; j < KNN; ++j) { od[j] = __shfl_xor(bd[j], m, 64); oi[j] = __shfl_xor(bi[j], m, 64); }
        float md[KNN]; int mi[KNN]; int a = 0, b = 0;
#pragma unroll
        for (int j = 0; j < KNN; ++j) {
            bool takeA = (bd[a] < od[b]) || (bd[a] == od[b] && bi[a] <= oi[b]);
            if (takeA) { md[j]=bd[a]; mi[j]=bi[a]; ++a; } else { md[j]=od[b]; mi[j]=oi[b]; ++b; }
        }
#pragma unroll
        for (int j = 0; j < KNN; ++j) { bd[j]=md[j]; bi[j]=mi[j]; }
    }
    if (lane == 0) {
#pragma unroll
        for (int j = 0; j < KNN; ++j) {
            out[wave*KNN+j] = bd[j];
            out[NQ*KNN + wave*KNN + j] = (float)bi[j];
        }
    }
}

extern "C" void kernel_launch(void* const* d_in, const int* in_sizes, int n_in,
                              void* d_out, int out_size, void* d_ws, size_t ws_size,
                              hipStream_t stream) {
    const float* points  = (const float*)d_in[0];
    const float* queries = (const float*)d_in[1];
    float* out = (float*)d_out;

    if (ws_size < (size_t)WS_NEED) {
        knn_fallback<<<(NQ * 64 + 255) / 256, 256, 0, stream>>>(points, queries, out);
        return;
    }

    char* ws = (char*)d_ws;
    float4* packed = (float4*)(ws + PK_OFF);
    int*    cnt    = (int*)(ws + CNT_OFF);
    float*  dl     = (float*)(ws + DL_OFF);
    int*    il     = (int*)(ws + IL_OFF);

    pack_kernel<<<NPAD / 256, 256, 0, stream>>>(points, packed);
    (void)hipMemsetAsync(cnt, 0, NQ * NCHUNK * sizeof(int), stream);
    knn_main<<<NWAVE / 4, 256, 0, stream>>>(packed, queries, cnt, dl, il);
    knn_final<<<(NQ + 255) / 256, 256, 0, stream>>>(cnt, dl, il, points, queries, out);
}